// Round 4
// baseline (1030.161 us; speedup 1.0000x reference)
//
#include <hip/hip_runtime.h>
#include <math.h>

// ---------------------------------------------------------------------------
// N2V GCN edge model, fp32.
//   CSR build: cnt=indeg(dst); dinv=rsqrt(cnt+1); rp=exscan; srcs bucketed
//   L1: A = x@W1 ; B = relu(gatherCSR(A) + A*dinv^2 + b1)
//   L2: A = B@W2 ; B = relu(gatherCSR(A) + A*dinv^2 + b2)
//   head: feat@M1 = u@M1a + v@M1b + |u-v|@M1c + (u*v)@M1d
//         Pa=h2@M1a+mb1, Pb=h2@M1b precomputed per NODE (linear terms) ->
//         per-pair GEMM only does the 2 nonlinear blocks (FLOPs halved).
// Round-4: k_mm_sr = weights-in-VGPR + node-row-via-s_load matmul (pure
// v_fma v,s,v inner loop); head_pb with halved K-blocks; ws_size-guarded
// fallback to round-3 head if workspace can't fit Pb.
// ---------------------------------------------------------------------------

__global__ void k_count_int(const int* __restrict__ dst, int* __restrict__ cnt, int e) {
  int i = blockIdx.x * blockDim.x + threadIdx.x;
  if (i < e) atomicAdd(&cnt[dst[i]], 1);
}

__global__ void k_dinv(const int* __restrict__ cnt, float* __restrict__ dinv, int n) {
  int i = blockIdx.x * blockDim.x + threadIdx.x;
  if (i < n) dinv[i] = rsqrtf((float)cnt[i] + 1.0f);
}

__global__ __launch_bounds__(256) void k_scan_block(const int* __restrict__ cnt,
                                                    int* __restrict__ rp,
                                                    int* __restrict__ bsum, int n) {
  __shared__ int wsum[4];
  int tid = threadIdx.x;
  int lane = tid & 63, w = tid >> 6;
  int idx = blockIdx.x * 1024 + tid * 4;
  int v0 = (idx + 0 < n) ? cnt[idx + 0] : 0;
  int v1 = (idx + 1 < n) ? cnt[idx + 1] : 0;
  int v2 = (idx + 2 < n) ? cnt[idx + 2] : 0;
  int v3 = (idx + 3 < n) ? cnt[idx + 3] : 0;
  int tot = v0 + v1 + v2 + v3;
  int x = tot;
#pragma unroll
  for (int off = 1; off < 64; off <<= 1) {
    int y = __shfl_up(x, off, 64);
    if (lane >= off) x += y;
  }
  if (lane == 63) wsum[w] = x;
  __syncthreads();
  int woff = 0;
  for (int i = 0; i < w; ++i) woff += wsum[i];
  int run = woff + x - tot;
  if (idx + 0 < n) rp[idx + 0] = run; run += v0;
  if (idx + 1 < n) rp[idx + 1] = run; run += v1;
  if (idx + 2 < n) rp[idx + 2] = run; run += v2;
  if (idx + 3 < n) rp[idx + 3] = run;
  if (tid == 255) bsum[blockIdx.x] = wsum[0] + wsum[1] + wsum[2] + wsum[3];
}

__global__ void k_scan_bsum(int* __restrict__ bsum, int nb) {
  int l = threadIdx.x;
  int v0 = (l < nb) ? bsum[l] : 0;
  int v1 = (64 + l < nb) ? bsum[64 + l] : 0;
  int i0 = v0;
#pragma unroll
  for (int off = 1; off < 64; off <<= 1) {
    int y = __shfl_up(i0, off, 64);
    if (l >= off) i0 += y;
  }
  int T0 = __shfl(i0, 63, 64);
  int i1 = v1;
#pragma unroll
  for (int off = 1; off < 64; off <<= 1) {
    int y = __shfl_up(i1, off, 64);
    if (l >= off) i1 += y;
  }
  if (l < nb) bsum[l] = i0 - v0;
  if (64 + l < nb) bsum[64 + l] = T0 + i1 - v1;
}

__global__ void k_scan_add(int* __restrict__ rp, const int* __restrict__ bsum,
                           int n, int e) {
  int i = blockIdx.x * blockDim.x + threadIdx.x;
  if (i < n) rp[i] += bsum[i >> 10];
  if (i == 0) rp[n] = e;
}

__global__ void k_fill(const int* __restrict__ src, const int* __restrict__ dst,
                       int* __restrict__ cur, int* __restrict__ srcs, int e) {
  int i = blockIdx.x * blockDim.x + threadIdx.x;
  if (i >= e) return;
  int pos = atomicAdd(&cur[dst[i]], 1);
  srcs[pos] = src[i];
}

// ---------------------------------------------------------------------------
// Scalar-row GEMM: OUT[n][lane] = sum_k IN[n][k] * W[k][lane] (+ bias[lane]).
// Wave holds its W column (lane) in K VGPRs; the node row is wave-uniform ->
// compiler emits s_load bursts; inner loop is v_fma(v, s, v). Coalesced store.
// 4 waves/block, each wave a chunk of npw nodes.
// ---------------------------------------------------------------------------
template <int K, bool BIAS>
__global__ __launch_bounds__(256) void k_mm_sr(const float* __restrict__ IN,
                                               const float* __restrict__ W,
                                               const float* __restrict__ bias,
                                               float* __restrict__ OUT,
                                               int n, int npw) {
  const int lane = threadIdx.x & 63;
  const int w = __builtin_amdgcn_readfirstlane(threadIdx.x >> 6);
  float wreg[K];
#pragma unroll
  for (int k = 0; k < K; ++k) wreg[k] = W[k * 64 + lane];
  float breg = BIAS ? bias[lane] : 0.f;
  const int base = (blockIdx.x * 4 + w) * npw;
  for (int i = 0; i < npw; ++i) {
    int node = base + i;
    if (node >= n) return;  // wave-uniform
    const float* __restrict__ hr = IN + (size_t)node * K;
    float a0 = breg, a1 = 0.f, a2 = 0.f, a3 = 0.f;
#pragma unroll
    for (int k = 0; k < K; k += 4) {
      a0 = fmaf(hr[k + 0], wreg[k + 0], a0);
      a1 = fmaf(hr[k + 1], wreg[k + 1], a1);
      a2 = fmaf(hr[k + 2], wreg[k + 2], a2);
      a3 = fmaf(hr[k + 3], wreg[k + 3], a3);
    }
    OUT[(size_t)node * 64 + lane] = (a0 + a1) + (a2 + a3);
  }
}

// one wave per node, 4 edge-groups of 16 lanes (round-3 gather, unchanged).
__global__ void k_gather(const float* __restrict__ hlin, const int* __restrict__ rp,
                         const int* __restrict__ srcs, const float* __restrict__ dinv,
                         const float* __restrict__ bias, float* __restrict__ outB,
                         int n) {
  int warp = threadIdx.x >> 6, lane = threadIdx.x & 63;
  int node = blockIdx.x * 4 + warp;
  if (node >= n) return;
  int g = lane >> 4, l16 = lane & 15;
  int beg = rp[node], end = rp[node + 1];
  float dn = dinv[node];
  float ax = 0.f, ay = 0.f, az = 0.f, aw = 0.f;
  for (int k = beg + g; k < end; k += 4) {
    int s = srcs[k];
    float c = dinv[s] * dn;
    float4 h = *(const float4*)(hlin + (size_t)s * 64 + l16 * 4);
    ax = fmaf(h.x, c, ax);
    ay = fmaf(h.y, c, ay);
    az = fmaf(h.z, c, az);
    aw = fmaf(h.w, c, aw);
  }
#pragma unroll
  for (int off = 16; off < 64; off <<= 1) {
    ax += __shfl_xor(ax, off, 64);
    ay += __shfl_xor(ay, off, 64);
    az += __shfl_xor(az, off, 64);
    aw += __shfl_xor(aw, off, 64);
  }
  if (g == 0) {
    float4 hs = *(const float4*)(hlin + (size_t)node * 64 + l16 * 4);
    float4 bb = *(const float4*)(bias + l16 * 4);
    float dd = dn * dn;
    float4 o;
    o.x = ax + hs.x * dd + bb.x;
    o.y = ay + hs.y * dd + bb.y;
    o.z = az + hs.z * dd + bb.z;
    o.w = aw + hs.w * dd + bb.w;
    o.x = o.x > 0.f ? o.x : 0.f;
    o.y = o.y > 0.f ? o.y : 0.f;
    o.z = o.z > 0.f ? o.z : 0.f;
    o.w = o.w > 0.f ? o.w : 0.f;
    *(float4*)(outB + (size_t)node * 64 + l16 * 4) = o;
  }
}

// ---------------------------------------------------------------------------
// Edge head with precomputed linear terms (Pa = h@M1a + mb1, Pb = h@M1b).
// 512 threads = 8 waves, 128 pairs/block. Wave w owns cols [8w,8w+8);
// lane owns pairs (2*lane, 2*lane+1).
// Staging computes d=|u-v|, m=u*v into interleaved LDS dm[j][{d,m}x128pairs]
// -> one ds_read_b128 per t feeds 32 FMAs; only 2 scalar bursts per t.
// acc-init = random float4 gathers of Pa[a], Pb[b] (issued before the loop,
// consumed in the epilogue so they stay in flight under the GEMM).
// ---------------------------------------------------------------------------
__global__ __launch_bounds__(512) void k_edge_head_pb(
    const float* __restrict__ H, const int* __restrict__ ep,
    const float* __restrict__ M1, const float* __restrict__ Pa,
    const float* __restrict__ Pb, const float* __restrict__ M2,
    const float* __restrict__ mb2, float* __restrict__ out, int p_total) {
  __shared__ float dm[64][256];     // [j][2*pair + {0:d,1:m}]
  __shared__ float part[8][128];
  __shared__ int ab[2][128];

  const int tid = threadIdx.x;
  const int pair0 = blockIdx.x * 128;

  // ---- stage: thread (pi, q) computes d,m for 16-row chunk q of pair pi
  {
    const int pi = tid & 127;
    const int q = tid >> 7;  // 0..3
    const int gp = pair0 + pi;
    if (gp < p_total) {
      int a = ep[gp];
      int b = ep[p_total + gp];
      if (q == 0) { ab[0][pi] = a; ab[1][pi] = b; }
      const float4* ua = (const float4*)(H + (size_t)a * 64 + q * 16);
      const float4* vb = (const float4*)(H + (size_t)b * 64 + q * 16);
#pragma unroll
      for (int r = 0; r < 4; ++r) {
        float4 uu = ua[r];
        float4 vv = vb[r];
        int j = q * 16 + r * 4;
        *(float2*)&dm[j + 0][2 * pi] = make_float2(fabsf(uu.x - vv.x), uu.x * vv.x);
        *(float2*)&dm[j + 1][2 * pi] = make_float2(fabsf(uu.y - vv.y), uu.y * vv.y);
        *(float2*)&dm[j + 2][2 * pi] = make_float2(fabsf(uu.z - vv.z), uu.z * vv.z);
        *(float2*)&dm[j + 3][2 * pi] = make_float2(fabsf(uu.w - vv.w), uu.w * vv.w);
      }
    } else {
#pragma unroll
      for (int r = 0; r < 4; ++r) {
        int j = q * 16 + r * 4;
        *(float2*)&dm[j + 0][2 * pi] = make_float2(0.f, 0.f);
        *(float2*)&dm[j + 1][2 * pi] = make_float2(0.f, 0.f);
        *(float2*)&dm[j + 2][2 * pi] = make_float2(0.f, 0.f);
        *(float2*)&dm[j + 3][2 * pi] = make_float2(0.f, 0.f);
      }
    }
  }
  __syncthreads();

  const int lane = tid & 63;
  const int w = tid >> 6;
  const int cg = __builtin_amdgcn_readfirstlane(w);
  const int p0 = 2 * lane;
  const int gp0 = pair0 + p0, gp1 = gp0 + 1;

  // acc-init gathers (consumed in epilogue; stay in flight during the loop)
  float4 z4 = make_float4(0.f, 0.f, 0.f, 0.f);
  float4 qa0 = z4, qa1 = z4, qb0 = z4, qb1 = z4;
  float4 ra0 = z4, ra1 = z4, rb0 = z4, rb1 = z4;
  if (gp0 < p_total) {
    int a = ab[0][p0], b = ab[1][p0];
    const float4* pa = (const float4*)(Pa + (size_t)a * 64 + cg * 8);
    const float4* pb = (const float4*)(Pb + (size_t)b * 64 + cg * 8);
    qa0 = pa[0]; qa1 = pa[1]; qb0 = pb[0]; qb1 = pb[1];
  }
  if (gp1 < p_total) {
    int a = ab[0][p0 + 1], b = ab[1][p0 + 1];
    const float4* pa = (const float4*)(Pa + (size_t)a * 64 + cg * 8);
    const float4* pb = (const float4*)(Pb + (size_t)b * 64 + cg * 8);
    ra0 = pa[0]; ra1 = pa[1]; rb0 = pb[0]; rb1 = pb[1];
  }

  float acc0[8], acc1[8];
#pragma unroll
  for (int c = 0; c < 8; ++c) { acc0[c] = 0.f; acc1[c] = 0.f; }

#pragma unroll 2
  for (int t = 0; t < 64; ++t) {
    float4 f = *(const float4*)&dm[t][4 * lane];  // d0,m0,d1,m1
    const float* r2 = M1 + (size_t)(128 + t) * 64 + cg * 8;  // |u-v| block
    const float* r3 = r2 + 64 * 64;                          // u*v block
#pragma unroll
    for (int c = 0; c < 8; ++c) {
      float w2 = r2[c], w3 = r3[c];
      acc0[c] = fmaf(f.x, w2, acc0[c]);
      acc0[c] = fmaf(f.y, w3, acc0[c]);
      acc1[c] = fmaf(f.z, w2, acc1[c]);
      acc1[c] = fmaf(f.w, w3, acc1[c]);
    }
  }

  float i0[8] = {qa0.x + qb0.x, qa0.y + qb0.y, qa0.z + qb0.z, qa0.w + qb0.w,
                 qa1.x + qb1.x, qa1.y + qb1.y, qa1.z + qb1.z, qa1.w + qb1.w};
  float i1[8] = {ra0.x + rb0.x, ra0.y + rb0.y, ra0.z + rb0.z, ra0.w + rb0.w,
                 ra1.x + rb1.x, ra1.y + rb1.y, ra1.z + rb1.z, ra1.w + rb1.w};
  float part0 = 0.f, part1 = 0.f;
#pragma unroll
  for (int c = 0; c < 8; ++c) {
    float m2 = M2[cg * 8 + c];
    float z0 = acc0[c] + i0[c]; z0 = z0 > 0.f ? z0 : 0.f;
    float z1 = acc1[c] + i1[c]; z1 = z1 > 0.f ? z1 : 0.f;
    part0 = fmaf(z0, m2, part0);
    part1 = fmaf(z1, m2, part1);
  }
  part[w][p0] = part0;
  part[w][p0 + 1] = part1;
  __syncthreads();

  if (tid < 128) {
    int gp = pair0 + tid;
    if (gp < p_total) {
      float s = 0.f;
#pragma unroll
      for (int w8 = 0; w8 < 8; ++w8) s += part[w8][tid];
      out[gp] = s + mb2[0];
    }
  }
}

// ---------------------------------------------------------------------------
// Fallback head (round-3 kernel, full 4-block GEMM) if workspace lacks Pb.
// ---------------------------------------------------------------------------
__global__ __launch_bounds__(512) void k_edge_head_fb(
    const float* __restrict__ H, const int* __restrict__ ep,
    const float* __restrict__ M1, const float* __restrict__ mb1,
    const float* __restrict__ M2, const float* __restrict__ mb2,
    float* __restrict__ out, int p_total) {
  __shared__ float u_lds[64][128];
  __shared__ float v_lds[64][128];
  __shared__ float part_lds[8][128];

  const int tid = threadIdx.x;
  const int pair0 = blockIdx.x * 128;
  {
    const int pi = tid & 127;
    const int q = tid >> 7;
    const int gp = pair0 + pi;
    if (gp < p_total) {
      int a = ep[gp];
      int b = ep[p_total + gp];
      const float4* ua = (const float4*)(H + (size_t)a * 64 + q * 16);
      const float4* vb = (const float4*)(H + (size_t)b * 64 + q * 16);
#pragma unroll
      for (int r = 0; r < 4; ++r) {
        float4 uu = ua[r];
        float4 vv = vb[r];
        int j = q * 16 + r * 4;
        u_lds[j + 0][pi] = uu.x; u_lds[j + 1][pi] = uu.y;
        u_lds[j + 2][pi] = uu.z; u_lds[j + 3][pi] = uu.w;
        v_lds[j + 0][pi] = vv.x; v_lds[j + 1][pi] = vv.y;
        v_lds[j + 2][pi] = vv.z; v_lds[j + 3][pi] = vv.w;
      }
    } else {
#pragma unroll
      for (int r = 0; r < 4; ++r) {
        int j = q * 16 + r * 4;
        u_lds[j + 0][pi] = 0.f; u_lds[j + 1][pi] = 0.f;
        u_lds[j + 2][pi] = 0.f; u_lds[j + 3][pi] = 0.f;
        v_lds[j + 0][pi] = 0.f; v_lds[j + 1][pi] = 0.f;
        v_lds[j + 2][pi] = 0.f; v_lds[j + 3][pi] = 0.f;
      }
    }
  }
  __syncthreads();

  const int lane = tid & 63;
  const int w = tid >> 6;
  const int cg = __builtin_amdgcn_readfirstlane(w);
  const float* __restrict__ M1w = M1 + cg * 8;
  const int p0 = 2 * lane;

  float acc0[8], acc1[8];
#pragma unroll
  for (int c = 0; c < 8; ++c) { acc0[c] = 0.f; acc1[c] = 0.f; }

#pragma unroll 2
  for (int t = 0; t < 64; ++t) {
    float2 uu = *(const float2*)&u_lds[t][p0];
    float2 vv = *(const float2*)&v_lds[t][p0];
    float d0 = fabsf(uu.x - vv.x), m0 = uu.x * vv.x;
    float d1 = fabsf(uu.y - vv.y), m1 = uu.y * vv.y;
    const float* r0 = M1w + t * 64;
    const float* r1 = M1w + (t + 64) * 64;
    const float* r2 = M1w + (t + 128) * 64;
    const float* r3 = M1w + (t + 192) * 64;
#pragma unroll
    for (int c = 0; c < 8; ++c) {
      float w0 = r0[c], w1 = r1[c], w2 = r2[c], w3 = r3[c];
      acc0[c] = fmaf(uu.x, w0, acc0[c]);
      acc0[c] = fmaf(vv.x, w1, acc0[c]);
      acc0[c] = fmaf(d0, w2, acc0[c]);
      acc0[c] = fmaf(m0, w3, acc0[c]);
      acc1[c] = fmaf(uu.y, w0, acc1[c]);
      acc1[c] = fmaf(vv.y, w1, acc1[c]);
      acc1[c] = fmaf(d1, w2, acc1[c]);
      acc1[c] = fmaf(m1, w3, acc1[c]);
    }
  }

  float part0 = 0.f, part1 = 0.f;
#pragma unroll
  for (int c = 0; c < 8; ++c) {
    float bb = mb1[cg * 8 + c];
    float m2 = M2[cg * 8 + c];
    float z0 = acc0[c] + bb; z0 = z0 > 0.f ? z0 : 0.f;
    float z1 = acc1[c] + bb; z1 = z1 > 0.f ? z1 : 0.f;
    part0 = fmaf(z0, m2, part0);
    part1 = fmaf(z1, m2, part1);
  }
  part_lds[w][p0] = part0;
  part_lds[w][p0 + 1] = part1;
  __syncthreads();

  if (tid < 128) {
    int gp = pair0 + tid;
    if (gp < p_total) {
      float s = 0.f;
#pragma unroll
      for (int w8 = 0; w8 < 8; ++w8) s += part_lds[w8][tid];
      out[gp] = s + mb2[0];
    }
  }
}

extern "C" void kernel_launch(void* const* d_in, const int* in_sizes, int n_in,
                              void* d_out, int out_size, void* d_ws, size_t ws_size,
                              hipStream_t stream) {
  const float* x   = (const float*)d_in[0];
  const int*   gei = (const int*)d_in[1];
  const int*   ep  = (const int*)d_in[2];
  const float* W1  = (const float*)d_in[3];
  const float* b1  = (const float*)d_in[4];
  const float* W2  = (const float*)d_in[5];
  const float* b2  = (const float*)d_in[6];
  const float* M1  = (const float*)d_in[7];
  const float* mb1 = (const float*)d_in[8];
  const float* M2  = (const float*)d_in[9];
  const float* mb2 = (const float*)d_in[10];
  float* out = (float*)d_out;

  const int N = in_sizes[0] / 128;
  const int E = in_sizes[1] / 2;
  const int P = in_sizes[2] / 2;
  const int* src = gei;
  const int* dst = gei + E;

  char* ws = (char*)d_ws;
  auto align256 = [](size_t b) { return (b + 255) & ~(size_t)255; };
  size_t degBytes = align256((size_t)N * 4);
  size_t hBytes   = align256((size_t)N * 64 * 4);
  size_t cntBytes = align256((size_t)N * 4);
  size_t rpBytes  = align256((size_t)(N + 1) * 4);
  size_t srcBytes = align256((size_t)E * 4);
  size_t bsumBytes = 256 * 4;

  size_t off = 0;
  float* dinv = (float*)(ws + off); off += degBytes;
  float* A    = (float*)(ws + off); off += hBytes;   // hlin / later Pa
  float* B    = (float*)(ws + off); off += hBytes;   // h out (h2 for head)
  int*   cnt  = (int*)(ws + off);   off += cntBytes;
  int*   rp   = (int*)(ws + off);   off += rpBytes;
  int*   srcs = (int*)(ws + off);   off += srcBytes;
  int*   bsum = (int*)(ws + off);   off += bsumBytes;
  float* Pb   = (float*)(ws + off); off += hBytes;   // only if it fits
  const bool have_pb = (ws_size >= off);

  const int BLK = 256;
  const int nb = (N + 1023) / 1024;  // <=128 supported (N<=131072)
  const int NPW = 32;                 // nodes per wave in k_mm_sr
  const int mmGrid = (N + 4 * NPW - 1) / (4 * NPW);

  // ---- CSR build + normalization ----
  hipMemsetAsync(cnt, 0, (size_t)N * 4, stream);
  k_count_int<<<(E + BLK - 1) / BLK, BLK, 0, stream>>>(dst, cnt, E);
  k_dinv<<<(N + BLK - 1) / BLK, BLK, 0, stream>>>(cnt, dinv, N);
  k_scan_block<<<nb, BLK, 0, stream>>>(cnt, rp, bsum, N);
  k_scan_bsum<<<1, 64, 0, stream>>>(bsum, nb);
  k_scan_add<<<(N + BLK - 1) / BLK, BLK, 0, stream>>>(rp, bsum, N, E);
  hipMemcpyAsync(cnt, rp, (size_t)N * 4, hipMemcpyDeviceToDevice, stream);
  k_fill<<<(E + BLK - 1) / BLK, BLK, 0, stream>>>(src, dst, cnt, srcs, E);

  // ---- layer 1 ----
  k_mm_sr<128, false><<<mmGrid, BLK, 0, stream>>>(x, W1, nullptr, A, N, NPW);
  k_gather<<<(N + 3) / 4, BLK, 0, stream>>>(A, rp, srcs, dinv, b1, B, N);

  // ---- layer 2 ----
  k_mm_sr<64, false><<<mmGrid, BLK, 0, stream>>>(B, W2, nullptr, A, N, NPW);
  k_gather<<<(N + 3) / 4, BLK, 0, stream>>>(A, rp, srcs, dinv, b2, B, N);

  // ---- edge head ----
  if (have_pb) {
    // Pa = h2@M1a + mb1 (into A, dead now); Pb = h2@M1b
    k_mm_sr<64, true><<<mmGrid, BLK, 0, stream>>>(B, M1, mb1, A, N, NPW);
    k_mm_sr<64, false><<<mmGrid, BLK, 0, stream>>>(B, M1 + 64 * 64, nullptr, Pb, N, NPW);
    k_edge_head_pb<<<(P + 127) / 128, 512, 0, stream>>>(B, ep, M1, A, Pb, M2, mb2,
                                                        out, P);
  } else {
    k_edge_head_fb<<<(P + 127) / 128, 512, 0, stream>>>(B, ep, M1, mb1, M2, mb2,
                                                        out, P);
  }
}

// Round 6
// 553.752 us; speedup vs baseline: 1.8603x; 1.8603x over previous
//
#include <hip/hip_runtime.h>
#include <math.h>

// ---------------------------------------------------------------------------
// N2V GCN edge model, fp32.
//   CSR build: cnt=indeg(dst); dinv=rsqrt(cnt+1); rp=exscan; srcs bucketed
//   L1: A = x@W1 ; B = relu(gatherCSR(A) + A*dinv^2 + b1)
//   L2: A = B@W2 ; B = relu(gatherCSR(A) + A*dinv^2 + b2)
//   head: per pair: feat=[u,v,|u-v|,u*v]; z=relu(feat@M1+mb1); out=z@M2+mb2
// Round-6: fix round-5's gather bug — the shfl-broadcast loop had divergent
// trip counts per 16-lane group, so tail-iteration ds_bpermute read from
// exec-INACTIVE source lanes (undefined). Now wave-uniform: all lanes run
// ceil(m/4) iterations; out-of-range k broadcasts (idx=0, cf=0) -> zero
// contribution, branch-free, every shuffle source active.
// Head keeps round-5 split-K staging (32 rows/phase, 36KB LDS -> 4 blk/CU).
// ---------------------------------------------------------------------------

__global__ void k_count_int(const int* __restrict__ dst, int* __restrict__ cnt, int e) {
  int i = blockIdx.x * blockDim.x + threadIdx.x;
  if (i < e) atomicAdd(&cnt[dst[i]], 1);
}

__global__ void k_dinv(const int* __restrict__ cnt, float* __restrict__ dinv, int n) {
  int i = blockIdx.x * blockDim.x + threadIdx.x;
  if (i < n) dinv[i] = rsqrtf((float)cnt[i] + 1.0f);  // self-loop included
}

__global__ __launch_bounds__(256) void k_scan_block(const int* __restrict__ cnt,
                                                    int* __restrict__ rp,
                                                    int* __restrict__ bsum, int n) {
  __shared__ int wsum[4];
  int tid = threadIdx.x;
  int lane = tid & 63, w = tid >> 6;
  int idx = blockIdx.x * 1024 + tid * 4;
  int v0 = (idx + 0 < n) ? cnt[idx + 0] : 0;
  int v1 = (idx + 1 < n) ? cnt[idx + 1] : 0;
  int v2 = (idx + 2 < n) ? cnt[idx + 2] : 0;
  int v3 = (idx + 3 < n) ? cnt[idx + 3] : 0;
  int tot = v0 + v1 + v2 + v3;
  int x = tot;
#pragma unroll
  for (int off = 1; off < 64; off <<= 1) {
    int y = __shfl_up(x, off, 64);
    if (lane >= off) x += y;
  }
  if (lane == 63) wsum[w] = x;
  __syncthreads();
  int woff = 0;
  for (int i = 0; i < w; ++i) woff += wsum[i];
  int run = woff + x - tot;
  if (idx + 0 < n) rp[idx + 0] = run; run += v0;
  if (idx + 1 < n) rp[idx + 1] = run; run += v1;
  if (idx + 2 < n) rp[idx + 2] = run; run += v2;
  if (idx + 3 < n) rp[idx + 3] = run;
  if (tid == 255) bsum[blockIdx.x] = wsum[0] + wsum[1] + wsum[2] + wsum[3];
}

__global__ void k_scan_bsum(int* __restrict__ bsum, int nb) {
  int l = threadIdx.x;
  int v0 = (l < nb) ? bsum[l] : 0;
  int v1 = (64 + l < nb) ? bsum[64 + l] : 0;
  int i0 = v0;
#pragma unroll
  for (int off = 1; off < 64; off <<= 1) {
    int y = __shfl_up(i0, off, 64);
    if (l >= off) i0 += y;
  }
  int T0 = __shfl(i0, 63, 64);
  int i1 = v1;
#pragma unroll
  for (int off = 1; off < 64; off <<= 1) {
    int y = __shfl_up(i1, off, 64);
    if (l >= off) i1 += y;
  }
  if (l < nb) bsum[l] = i0 - v0;
  if (64 + l < nb) bsum[64 + l] = T0 + i1 - v1;
}

__global__ void k_scan_add(int* __restrict__ rp, const int* __restrict__ bsum,
                           int n, int e) {
  int i = blockIdx.x * blockDim.x + threadIdx.x;
  if (i < n) rp[i] += bsum[i >> 10];
  if (i == 0) rp[n] = e;
}

__global__ void k_fill(const int* __restrict__ src, const int* __restrict__ dst,
                       int* __restrict__ cur, int* __restrict__ srcs, int e) {
  int i = blockIdx.x * blockDim.x + threadIdx.x;
  if (i >= e) return;
  int pos = atomicAdd(&cur[dst[i]], 1);
  srcs[pos] = src[i];
}

// A[node][j] = sum_k x[node][k] * W[k][j]   (K=128, H=64), one wave per node
__global__ void k_matmul_in(const float* __restrict__ x, const float* __restrict__ W,
                            float* __restrict__ out, int n) {
  __shared__ float xs[4][128];
  int warp = threadIdx.x >> 6, lane = threadIdx.x & 63;
  int node = blockIdx.x * 4 + warp;
  if (node < n) {
    const float* xr = x + (size_t)node * 128;
    xs[warp][lane]      = xr[lane];
    xs[warp][64 + lane] = xr[64 + lane];
  }
  __syncthreads();
  if (node >= n) return;
  float acc = 0.f;
#pragma unroll 8
  for (int k = 0; k < 128; ++k) acc += xs[warp][k] * W[k * 64 + lane];
  out[(size_t)node * 64 + lane] = acc;
}

// A[node][j] = sum_k h[node][k] * W[k][j]   (K=64, H=64), one wave per node
__global__ void k_matmul_hid(const float* __restrict__ h, const float* __restrict__ W,
                             float* __restrict__ out, int n) {
  __shared__ float hs[4][64];
  int warp = threadIdx.x >> 6, lane = threadIdx.x & 63;
  int node = blockIdx.x * 4 + warp;
  if (node < n) hs[warp][lane] = h[(size_t)node * 64 + lane];
  __syncthreads();
  if (node >= n) return;
  float acc = 0.f;
#pragma unroll 8
  for (int k = 0; k < 64; ++k) acc += hs[warp][k] * W[k * 64 + lane];
  out[(size_t)node * 64 + lane] = acc;
}

// one wave per node. Bulk phase: 64 lanes load up to 64 (src, coef) once per
// chunk (coalesced srcs + parallel dinv gather). Accumulate loop is
// WAVE-UNIFORM: all lanes run iters=ceil(m/4) iterations; group g takes
// k=g+4*i. k>=m broadcasts (idx=0, cf=0) -> zero contribution. Every shuffle
// source lane is active (fixes round-5 undefined divergent bpermute).
__global__ void k_gather(const float* __restrict__ hlin, const int* __restrict__ rp,
                         const int* __restrict__ srcs, const float* __restrict__ dinv,
                         const float* __restrict__ bias, float* __restrict__ outB,
                         int n) {
  int warp = threadIdx.x >> 6, lane = threadIdx.x & 63;
  int node = blockIdx.x * 4 + warp;
  if (node >= n) return;
  int g = lane >> 4, l16 = lane & 15;
  int beg = rp[node], end = rp[node + 1];
  int deg = end - beg;
  float dn = dinv[node];
  float ax = 0.f, ay = 0.f, az = 0.f, aw = 0.f;
  for (int base = 0; base < deg; base += 64) {
    int rem = deg - base;
    int m = rem < 64 ? rem : 64;
    int idx = 0;
    float cf = 0.f;
    if (lane < m) {
      int s = srcs[beg + base + lane];
      idx = s;
      cf = dinv[s] * dn;
    }
    int iters = (m + 3) >> 2;  // wave-uniform trip count
    for (int i = 0; i < iters; ++i) {
      int k = g + 4 * i;  // <= 63 always; k>=m harmless (cf=0)
      int s = __shfl(idx, k, 64);
      float c = __shfl(cf, k, 64);
      float4 h = *(const float4*)(hlin + (size_t)s * 64 + l16 * 4);
      ax = fmaf(h.x, c, ax);
      ay = fmaf(h.y, c, ay);
      az = fmaf(h.z, c, az);
      aw = fmaf(h.w, c, aw);
    }
  }
  // reduce the 4 groups (lanes l16, l16+16, l16+32, l16+48)
#pragma unroll
  for (int off = 16; off < 64; off <<= 1) {
    ax += __shfl_xor(ax, off, 64);
    ay += __shfl_xor(ay, off, 64);
    az += __shfl_xor(az, off, 64);
    aw += __shfl_xor(aw, off, 64);
  }
  if (g == 0) {
    float4 hs = *(const float4*)(hlin + (size_t)node * 64 + l16 * 4);
    float4 bb = *(const float4*)(bias + l16 * 4);
    float dd = dn * dn;
    float4 o;
    o.x = ax + hs.x * dd + bb.x;
    o.y = ay + hs.y * dd + bb.y;
    o.z = az + hs.z * dd + bb.z;
    o.w = aw + hs.w * dd + bb.w;
    o.x = o.x > 0.f ? o.x : 0.f;
    o.y = o.y > 0.f ? o.y : 0.f;
    o.z = o.z > 0.f ? o.z : 0.f;
    o.w = o.w > 0.f ? o.w : 0.f;
    *(float4*)(outB + (size_t)node * 64 + l16 * 4) = o;
  }
}

// ---------------------------------------------------------------------------
// Edge head: 512 threads = 8 waves, 128 pairs/block, split-K staging.
// Wave w owns cols [8w, 8w+8); lane owns pairs (2*lane, 2*lane+1).
// K (feature rows) processed in 2 phases of 32 rows; 36KB LDS -> 4 blocks/CU
// (2x the wave pool of the 68KB round-3 version, to hide M1 s_load bursts).
// ---------------------------------------------------------------------------
__global__ __launch_bounds__(512) void k_edge_head(
    const float* __restrict__ H, const int* __restrict__ ep,
    const float* __restrict__ M1, const float* __restrict__ mb1,
    const float* __restrict__ M2, const float* __restrict__ mb2,
    float* __restrict__ out, int p_total) {
  __shared__ float u_lds[32][128];   // [j][pair], current 32-row phase
  __shared__ float v_lds[32][128];
  __shared__ float part_lds[8][128];

  const int tid = threadIdx.x;
  const int pair0 = blockIdx.x * 128;
  const int pi = tid & 127;   // staging: pair
  const int q  = tid >> 7;    // staging: 8-row chunk within phase (0..3)
  const int gp_pi = pair0 + pi;
  const bool valid = gp_pi < p_total;
  int a = 0, b = 0;
  if (valid) {
    a = ep[gp_pi];
    b = ep[p_total + gp_pi];
  }

  const int lane = tid & 63;
  const int w = tid >> 6;  // 0..7
  const int cg = __builtin_amdgcn_readfirstlane(w);
  const float* __restrict__ M1w = M1 + cg * 8;
  const int p0 = 2 * lane;

  float acc0[8], acc1[8];
#pragma unroll
  for (int c = 0; c < 8; ++c) { acc0[c] = 0.f; acc1[c] = 0.f; }

#pragma unroll
  for (int ph = 0; ph < 2; ++ph) {
    if (ph) __syncthreads();  // previous phase fully consumed before overwrite
    // ---- stage rows [32*ph, 32*ph+32): thread (pi,q) covers rows q*8..q*8+8
    {
      int j = q * 8;
      if (valid) {
        const float4* ua = (const float4*)(H + (size_t)a * 64 + ph * 32 + j);
        const float4* vb = (const float4*)(H + (size_t)b * 64 + ph * 32 + j);
        float4 u0 = ua[0], u1 = ua[1];
        float4 v0 = vb[0], v1 = vb[1];
        u_lds[j + 0][pi] = u0.x; u_lds[j + 1][pi] = u0.y;
        u_lds[j + 2][pi] = u0.z; u_lds[j + 3][pi] = u0.w;
        u_lds[j + 4][pi] = u1.x; u_lds[j + 5][pi] = u1.y;
        u_lds[j + 6][pi] = u1.z; u_lds[j + 7][pi] = u1.w;
        v_lds[j + 0][pi] = v0.x; v_lds[j + 1][pi] = v0.y;
        v_lds[j + 2][pi] = v0.z; v_lds[j + 3][pi] = v0.w;
        v_lds[j + 4][pi] = v1.x; v_lds[j + 5][pi] = v1.y;
        v_lds[j + 6][pi] = v1.z; v_lds[j + 7][pi] = v1.w;
      } else {
#pragma unroll
        for (int r = 0; r < 8; ++r) {
          u_lds[j + r][pi] = 0.f;
          v_lds[j + r][pi] = 0.f;
        }
      }
    }
    __syncthreads();

    // ---- GEMM over this phase's 32 rows
#pragma unroll 2
    for (int t = 0; t < 32; ++t) {
      float2 uu = *(const float2*)&u_lds[t][p0];
      float2 vv = *(const float2*)&v_lds[t][p0];
      float d0 = fabsf(uu.x - vv.x), m0 = uu.x * vv.x;
      float d1 = fabsf(uu.y - vv.y), m1 = uu.y * vv.y;
      const int tt = ph * 32 + t;
      const float* r0 = M1w + tt * 64;          // u block, row tt
      const float* r1 = M1w + (tt + 64) * 64;   // v block
      const float* r2 = M1w + (tt + 128) * 64;  // |u-v| block
      const float* r3 = M1w + (tt + 192) * 64;  // u*v block
#pragma unroll
      for (int c = 0; c < 8; ++c) {
        float w0 = r0[c], w1 = r1[c], w2 = r2[c], w3 = r3[c];
        acc0[c] = fmaf(uu.x, w0, acc0[c]);
        acc0[c] = fmaf(vv.x, w1, acc0[c]);
        acc0[c] = fmaf(d0,  w2, acc0[c]);
        acc0[c] = fmaf(m0,  w3, acc0[c]);
        acc1[c] = fmaf(uu.y, w0, acc1[c]);
        acc1[c] = fmaf(vv.y, w1, acc1[c]);
        acc1[c] = fmaf(d1,  w2, acc1[c]);
        acc1[c] = fmaf(m1,  w3, acc1[c]);
      }
    }
  }

  // epilogue: z = relu(acc + mb1); partial = z . M2 over this wave's 8 cols
  float part0 = 0.f, part1 = 0.f;
#pragma unroll
  for (int c = 0; c < 8; ++c) {
    float bb = mb1[cg * 8 + c];
    float m2 = M2[cg * 8 + c];
    float z0 = acc0[c] + bb; z0 = z0 > 0.f ? z0 : 0.f;
    float z1 = acc1[c] + bb; z1 = z1 > 0.f ? z1 : 0.f;
    part0 = fmaf(z0, m2, part0);
    part1 = fmaf(z1, m2, part1);
  }
  part_lds[w][p0]     = part0;
  part_lds[w][p0 + 1] = part1;
  __syncthreads();

  if (tid < 128) {
    int gp = pair0 + tid;
    if (gp < p_total) {
      float s = 0.f;
#pragma unroll
      for (int w8 = 0; w8 < 8; ++w8) s += part_lds[w8][tid];
      out[gp] = s + mb2[0];
    }
  }
}

extern "C" void kernel_launch(void* const* d_in, const int* in_sizes, int n_in,
                              void* d_out, int out_size, void* d_ws, size_t ws_size,
                              hipStream_t stream) {
  const float* x   = (const float*)d_in[0];
  const int*   gei = (const int*)d_in[1];
  const int*   ep  = (const int*)d_in[2];
  const float* W1  = (const float*)d_in[3];
  const float* b1  = (const float*)d_in[4];
  const float* W2  = (const float*)d_in[5];
  const float* b2  = (const float*)d_in[6];
  const float* M1  = (const float*)d_in[7];
  const float* mb1 = (const float*)d_in[8];
  const float* M2  = (const float*)d_in[9];
  const float* mb2 = (const float*)d_in[10];
  float* out = (float*)d_out;

  const int N = in_sizes[0] / 128;
  const int E = in_sizes[1] / 2;
  const int P = in_sizes[2] / 2;
  const int* src = gei;
  const int* dst = gei + E;

  char* ws = (char*)d_ws;
  auto align256 = [](size_t b) { return (b + 255) & ~(size_t)255; };
  size_t degBytes  = align256((size_t)N * 4);
  size_t hBytes    = align256((size_t)N * 64 * 4);
  size_t cntBytes  = align256((size_t)N * 4);
  size_t rpBytes   = align256((size_t)(N + 1) * 4);
  size_t srcBytes  = align256((size_t)E * 4);

  float* dinv = (float*)ws;                                  // N
  float* A    = (float*)(ws + degBytes);                     // N x 64 (hlin)
  float* B    = (float*)(ws + degBytes + hBytes);            // N x 64 (h out)
  int*   cnt  = (int*)(ws + degBytes + 2 * hBytes);          // N (counts -> cursors)
  int*   rp   = (int*)(ws + degBytes + 2 * hBytes + cntBytes);            // N+1
  int*   srcs = (int*)(ws + degBytes + 2 * hBytes + cntBytes + rpBytes);  // E
  int*   bsum = (int*)(ws + degBytes + 2 * hBytes + cntBytes + rpBytes + srcBytes); // 128

  const int BLK = 256;
  const int nb = (N + 1023) / 1024;  // scan blocks; <=128 supported (N<=131072)

  // ---- CSR build + normalization ----
  hipMemsetAsync(cnt, 0, (size_t)N * 4, stream);
  k_count_int<<<(E + BLK - 1) / BLK, BLK, 0, stream>>>(dst, cnt, E);
  k_dinv<<<(N + BLK - 1) / BLK, BLK, 0, stream>>>(cnt, dinv, N);
  k_scan_block<<<nb, BLK, 0, stream>>>(cnt, rp, bsum, N);
  k_scan_bsum<<<1, 64, 0, stream>>>(bsum, nb);
  k_scan_add<<<(N + BLK - 1) / BLK, BLK, 0, stream>>>(rp, bsum, N, E);
  hipMemcpyAsync(cnt, rp, (size_t)N * 4, hipMemcpyDeviceToDevice, stream);  // cursors
  k_fill<<<(E + BLK - 1) / BLK, BLK, 0, stream>>>(src, dst, cnt, srcs, E);

  // ---- layer 1 ----
  k_matmul_in<<<(N + 3) / 4, BLK, 0, stream>>>(x, W1, A, N);
  k_gather<<<(N + 3) / 4, BLK, 0, stream>>>(A, rp, srcs, dinv, b1, B, N);

  // ---- layer 2 ----
  k_matmul_hid<<<(N + 3) / 4, BLK, 0, stream>>>(B, W2, A, N);
  k_gather<<<(N + 3) / 4, BLK, 0, stream>>>(A, rp, srcs, dinv, b2, B, N);

  // ---- edge head: 128 pairs per 512-thread block ----
  k_edge_head<<<(P + 127) / 128, 512, 0, stream>>>(B, ep, M1, mb1, M2, mb2, out, P);
}

// Round 7
// 468.336 us; speedup vs baseline: 2.1996x; 1.1824x over previous
//
#include <hip/hip_runtime.h>
#include <math.h>

// ---------------------------------------------------------------------------
// N2V GCN edge model, fp32.
//   CSR build: cnt=indeg(dst); dinv=rsqrt(cnt+1); rp=exscan; srcs+coefs bucketed
//   L1: A = x@W1 ; B = relu(gatherCSR(A) + A*dinv^2 + b1)
//   L2: A = B@W2 ; B = relu(gatherCSR(A) + A*dinv^2 + b2)
//   head: per pair: feat=[u,v,|u-v|,u*v]; z=relu(feat@M1+mb1); out=z@M2+mb2
// Round-7:
//   - head: 256 pairs/block, 4 pairs/lane (acc 8x4), 4 phases x 16 rows,
//     part-buffer union'd into u-buffer -> 32KB LDS, launch_bounds(512,6).
//     2x FMA per scalar M1 byte vs round-6.
//   - matmuls: W column in VGPRs (once/wave) + row staged lane-coalesced ->
//     LDS -> broadcast ds_read_b128. Kills the per-MAC stride-256B VMEM W
//     load. (Round-4's k_mm_sr failed on uniform-global ROW loads, not wreg.)
//   - k_fill also emits coefs[pos]=dinv[s]*dinv[d] -> gather inner loads are
//     2 coalesced streams (srcs, coefs), no dependent dinv gather.
// ---------------------------------------------------------------------------

__global__ void k_count_int(const int* __restrict__ dst, int* __restrict__ cnt, int e) {
  int i = blockIdx.x * blockDim.x + threadIdx.x;
  if (i < e) atomicAdd(&cnt[dst[i]], 1);
}

__global__ void k_dinv(const int* __restrict__ cnt, float* __restrict__ dinv, int n) {
  int i = blockIdx.x * blockDim.x + threadIdx.x;
  if (i < n) dinv[i] = rsqrtf((float)cnt[i] + 1.0f);  // self-loop included
}

__global__ __launch_bounds__(256) void k_scan_block(const int* __restrict__ cnt,
                                                    int* __restrict__ rp,
                                                    int* __restrict__ bsum, int n) {
  __shared__ int wsum[4];
  int tid = threadIdx.x;
  int lane = tid & 63, w = tid >> 6;
  int idx = blockIdx.x * 1024 + tid * 4;
  int v0 = (idx + 0 < n) ? cnt[idx + 0] : 0;
  int v1 = (idx + 1 < n) ? cnt[idx + 1] : 0;
  int v2 = (idx + 2 < n) ? cnt[idx + 2] : 0;
  int v3 = (idx + 3 < n) ? cnt[idx + 3] : 0;
  int tot = v0 + v1 + v2 + v3;
  int x = tot;
#pragma unroll
  for (int off = 1; off < 64; off <<= 1) {
    int y = __shfl_up(x, off, 64);
    if (lane >= off) x += y;
  }
  if (lane == 63) wsum[w] = x;
  __syncthreads();
  int woff = 0;
  for (int i = 0; i < w; ++i) woff += wsum[i];
  int run = woff + x - tot;
  if (idx + 0 < n) rp[idx + 0] = run; run += v0;
  if (idx + 1 < n) rp[idx + 1] = run; run += v1;
  if (idx + 2 < n) rp[idx + 2] = run; run += v2;
  if (idx + 3 < n) rp[idx + 3] = run;
  if (tid == 255) bsum[blockIdx.x] = wsum[0] + wsum[1] + wsum[2] + wsum[3];
}

__global__ void k_scan_bsum(int* __restrict__ bsum, int nb) {
  int l = threadIdx.x;
  int v0 = (l < nb) ? bsum[l] : 0;
  int v1 = (64 + l < nb) ? bsum[64 + l] : 0;
  int i0 = v0;
#pragma unroll
  for (int off = 1; off < 64; off <<= 1) {
    int y = __shfl_up(i0, off, 64);
    if (l >= off) i0 += y;
  }
  int T0 = __shfl(i0, 63, 64);
  int i1 = v1;
#pragma unroll
  for (int off = 1; off < 64; off <<= 1) {
    int y = __shfl_up(i1, off, 64);
    if (l >= off) i1 += y;
  }
  if (l < nb) bsum[l] = i0 - v0;
  if (64 + l < nb) bsum[64 + l] = T0 + i1 - v1;
}

__global__ void k_scan_add(int* __restrict__ rp, const int* __restrict__ bsum,
                           int n, int e) {
  int i = blockIdx.x * blockDim.x + threadIdx.x;
  if (i < n) rp[i] += bsum[i >> 10];
  if (i == 0) rp[n] = e;
}

// fill CSR buckets; also precompute per-edge coefficient.
__global__ void k_fill(const int* __restrict__ src, const int* __restrict__ dst,
                       int* __restrict__ cur, const float* __restrict__ dinv,
                       int* __restrict__ srcs, float* __restrict__ coefs, int e) {
  int i = blockIdx.x * blockDim.x + threadIdx.x;
  if (i >= e) return;
  int s = src[i], d = dst[i];
  int pos = atomicAdd(&cur[d], 1);
  srcs[pos] = s;
  coefs[pos] = dinv[s] * dinv[d];
}

// ---------------------------------------------------------------------------
// Matmul, W-in-VGPR: OUT[node][lane] = sum_k IN[node][k]*W[k][lane].
// Wave holds its W column in wreg[K] (loaded once). Node row staged per-lane
// coalesced -> LDS slice -> broadcast ds_read_b128 (4 k per read, 4 FMA each).
// No __syncthreads: intra-wave LDS RAW ordered by in-order DS pipe + lgkmcnt.
// Next row prefetched into regs under current node's compute.
// ---------------------------------------------------------------------------
template <int K>
__global__ __launch_bounds__(256) void k_matmul_w(const float* __restrict__ IN,
                                                  const float* __restrict__ W,
                                                  float* __restrict__ OUT,
                                                  int n, int npw) {
  __shared__ float rows[4][K];
  const int wv = threadIdx.x >> 6, lane = threadIdx.x & 63;
  float wreg[K];
#pragma unroll
  for (int k = 0; k < K; ++k) wreg[k] = W[k * 64 + lane];
  int base = (blockIdx.x * 4 + wv) * npw;
  if (base >= n) return;
  int nEnd = base + npw;
  if (nEnd > n) nEnd = n;
  float p0 = IN[(size_t)base * K + lane];
  float p1 = (K == 128) ? IN[(size_t)base * K + 64 + lane] : 0.f;
  for (int node = base; node < nEnd; ++node) {
    rows[wv][lane] = p0;
    if (K == 128) rows[wv][64 + lane] = p1;
    if (node + 1 < nEnd) {  // prefetch next row under this node's compute
      p0 = IN[(size_t)(node + 1) * K + lane];
      if (K == 128) p1 = IN[(size_t)(node + 1) * K + 64 + lane];
    }
    float a0 = 0.f, a1 = 0.f, a2 = 0.f, a3 = 0.f;
#pragma unroll
    for (int k = 0; k < K; k += 4) {
      float4 xk = *(const float4*)&rows[wv][k];
      a0 = fmaf(xk.x, wreg[k + 0], a0);
      a1 = fmaf(xk.y, wreg[k + 1], a1);
      a2 = fmaf(xk.z, wreg[k + 2], a2);
      a3 = fmaf(xk.w, wreg[k + 3], a3);
    }
    OUT[(size_t)node * 64 + lane] = (a0 + a1) + (a2 + a3);
  }
}

// one wave per node; wave-uniform shfl-broadcast accumulate (round-6 logic),
// with coefs[] stream instead of a dependent dinv[s] gather.
__global__ void k_gather(const float* __restrict__ hlin, const int* __restrict__ rp,
                         const int* __restrict__ srcs, const float* __restrict__ coefs,
                         const float* __restrict__ dinv,
                         const float* __restrict__ bias, float* __restrict__ outB,
                         int n) {
  int warp = threadIdx.x >> 6, lane = threadIdx.x & 63;
  int node = blockIdx.x * 4 + warp;
  if (node >= n) return;
  int g = lane >> 4, l16 = lane & 15;
  int beg = rp[node], end = rp[node + 1];
  int deg = end - beg;
  float dn = dinv[node];
  float ax = 0.f, ay = 0.f, az = 0.f, aw = 0.f;
  for (int base = 0; base < deg; base += 64) {
    int rem = deg - base;
    int m = rem < 64 ? rem : 64;
    int idx = 0;
    float cf = 0.f;
    if (lane < m) {
      idx = srcs[beg + base + lane];
      cf = coefs[beg + base + lane];
    }
    int iters = (m + 3) >> 2;  // wave-uniform trip count
    for (int i = 0; i < iters; ++i) {
      int k = g + 4 * i;  // <= 63 always; k>=m harmless (cf=0)
      int s = __shfl(idx, k, 64);
      float c = __shfl(cf, k, 64);
      float4 h = *(const float4*)(hlin + (size_t)s * 64 + l16 * 4);
      ax = fmaf(h.x, c, ax);
      ay = fmaf(h.y, c, ay);
      az = fmaf(h.z, c, az);
      aw = fmaf(h.w, c, aw);
    }
  }
#pragma unroll
  for (int off = 16; off < 64; off <<= 1) {
    ax += __shfl_xor(ax, off, 64);
    ay += __shfl_xor(ay, off, 64);
    az += __shfl_xor(az, off, 64);
    aw += __shfl_xor(aw, off, 64);
  }
  if (g == 0) {
    float4 hs = *(const float4*)(hlin + (size_t)node * 64 + l16 * 4);
    float4 bb = *(const float4*)(bias + l16 * 4);
    float dd = dn * dn;
    float4 o;
    o.x = ax + hs.x * dd + bb.x;
    o.y = ay + hs.y * dd + bb.y;
    o.z = az + hs.z * dd + bb.z;
    o.w = aw + hs.w * dd + bb.w;
    o.x = o.x > 0.f ? o.x : 0.f;
    o.y = o.y > 0.f ? o.y : 0.f;
    o.z = o.z > 0.f ? o.z : 0.f;
    o.w = o.w > 0.f ? o.w : 0.f;
    *(float4*)(outB + (size_t)node * 64 + l16 * 4) = o;
  }
}

// ---------------------------------------------------------------------------
// Edge head: 512 threads = 8 waves, 256 pairs/block, 4 pairs/lane.
// Wave w owns cols [8w, 8w+8); lane owns pairs 4*lane..4*lane+3.
// 4 phases x 16 rows; u buffer [16][256] at sbuf[0], v at sbuf[4096].
// Partials union'd into the u region after the last phase -> 32KB total LDS.
// 128 FMA per 32 scalar M1 floats per t (2x round-6 density).
// ---------------------------------------------------------------------------
__global__ __launch_bounds__(512, 6) void k_edge_head(
    const float* __restrict__ H, const int* __restrict__ ep,
    const float* __restrict__ M1, const float* __restrict__ mb1,
    const float* __restrict__ M2, const float* __restrict__ mb2,
    float* __restrict__ out, int p_total) {
  __shared__ float sbuf[8192];  // u:[0,4096) v:[4096,8192); parts reuse u

  const int tid = threadIdx.x;
  const int pair0 = blockIdx.x * 256;

  // staging identity: thread handles u (hf=0) or v (hf=1) of pair pi
  const int pi = tid & 255;
  const int hf = tid >> 8;
  const int gp_pi = pair0 + pi;
  const bool valid = gp_pi < p_total;
  int node = 0;
  if (valid) node = hf ? ep[p_total + gp_pi] : ep[gp_pi];
  float* __restrict__ myb = sbuf + hf * 4096;

  // gemm identity
  const int lane = tid & 63;
  const int w = tid >> 6;  // 0..7
  const int cg = __builtin_amdgcn_readfirstlane(w);
  const int p0 = 4 * lane;

  float acc[8][4];
#pragma unroll
  for (int c = 0; c < 8; ++c)
#pragma unroll
    for (int p = 0; p < 4; ++p) acc[c][p] = 0.f;

#pragma unroll
  for (int ph = 0; ph < 4; ++ph) {
    if (ph) __syncthreads();  // previous phase fully consumed
    // ---- stage 16 rows of this thread's matrix (u or v), pair pi
    if (valid) {
      const float4* hr = (const float4*)(H + (size_t)node * 64 + ph * 16);
      float4 c0 = hr[0], c1 = hr[1], c2 = hr[2], c3 = hr[3];
      myb[0 * 256 + pi]  = c0.x; myb[1 * 256 + pi]  = c0.y;
      myb[2 * 256 + pi]  = c0.z; myb[3 * 256 + pi]  = c0.w;
      myb[4 * 256 + pi]  = c1.x; myb[5 * 256 + pi]  = c1.y;
      myb[6 * 256 + pi]  = c1.z; myb[7 * 256 + pi]  = c1.w;
      myb[8 * 256 + pi]  = c2.x; myb[9 * 256 + pi]  = c2.y;
      myb[10 * 256 + pi] = c2.z; myb[11 * 256 + pi] = c2.w;
      myb[12 * 256 + pi] = c3.x; myb[13 * 256 + pi] = c3.y;
      myb[14 * 256 + pi] = c3.z; myb[15 * 256 + pi] = c3.w;
    } else {
#pragma unroll
      for (int j = 0; j < 16; ++j) myb[j * 256 + pi] = 0.f;
    }
    __syncthreads();

    // ---- GEMM over this phase's 16 feature rows
#pragma unroll 2
    for (int t = 0; t < 16; ++t) {
      float4 u4 = *(const float4*)&sbuf[t * 256 + p0];
      float4 v4 = *(const float4*)&sbuf[4096 + t * 256 + p0];
      float uu[4] = {u4.x, u4.y, u4.z, u4.w};
      float vv[4] = {v4.x, v4.y, v4.z, v4.w};
      float dd[4], mm[4];
#pragma unroll
      for (int p = 0; p < 4; ++p) {
        dd[p] = fabsf(uu[p] - vv[p]);
        mm[p] = uu[p] * vv[p];
      }
      const int tt = ph * 16 + t;
      const float* r0 = M1 + (size_t)tt * 64 + cg * 8;   // u block
      const float* r1 = r0 + 64 * 64;                    // v block
      const float* r2 = r0 + 128 * 64;                   // |u-v| block
      const float* r3 = r0 + 192 * 64;                   // u*v block
#pragma unroll
      for (int c = 0; c < 8; ++c) {
        float w0 = r0[c], w1 = r1[c], w2 = r2[c], w3 = r3[c];
#pragma unroll
        for (int p = 0; p < 4; ++p) {
          acc[c][p] = fmaf(uu[p], w0, acc[c][p]);
          acc[c][p] = fmaf(vv[p], w1, acc[c][p]);
          acc[c][p] = fmaf(dd[p], w2, acc[c][p]);
          acc[c][p] = fmaf(mm[p], w3, acc[c][p]);
        }
      }
    }
  }

  __syncthreads();  // all reads of sbuf done; reuse u region for partials

  // epilogue: per pair p: part = sum_c relu(acc+mb1)*M2 over this wave's 8 cols
#pragma unroll
  for (int p = 0; p < 4; ++p) {
    float part = 0.f;
#pragma unroll
    for (int c = 0; c < 8; ++c) {
      float z = acc[c][p] + mb1[cg * 8 + c];
      z = z > 0.f ? z : 0.f;
      part = fmaf(z, M2[cg * 8 + c], part);
    }
    sbuf[w * 256 + p0 + p] = part;
  }
  __syncthreads();

  if (tid < 256) {
    int gp = pair0 + tid;
    if (gp < p_total) {
      float s = 0.f;
#pragma unroll
      for (int w8 = 0; w8 < 8; ++w8) s += sbuf[w8 * 256 + tid];
      out[gp] = s + mb2[0];
    }
  }
}

extern "C" void kernel_launch(void* const* d_in, const int* in_sizes, int n_in,
                              void* d_out, int out_size, void* d_ws, size_t ws_size,
                              hipStream_t stream) {
  const float* x   = (const float*)d_in[0];
  const int*   gei = (const int*)d_in[1];
  const int*   ep  = (const int*)d_in[2];
  const float* W1  = (const float*)d_in[3];
  const float* b1  = (const float*)d_in[4];
  const float* W2  = (const float*)d_in[5];
  const float* b2  = (const float*)d_in[6];
  const float* M1  = (const float*)d_in[7];
  const float* mb1 = (const float*)d_in[8];
  const float* M2  = (const float*)d_in[9];
  const float* mb2 = (const float*)d_in[10];
  float* out = (float*)d_out;

  const int N = in_sizes[0] / 128;
  const int E = in_sizes[1] / 2;
  const int P = in_sizes[2] / 2;
  const int* src = gei;
  const int* dst = gei + E;

  char* ws = (char*)d_ws;
  auto align256 = [](size_t b) { return (b + 255) & ~(size_t)255; };
  size_t degBytes  = align256((size_t)N * 4);
  size_t hBytes    = align256((size_t)N * 64 * 4);
  size_t cntBytes  = align256((size_t)N * 4);
  size_t rpBytes   = align256((size_t)(N + 1) * 4);
  size_t srcBytes  = align256((size_t)E * 4);

  size_t off = 0;
  float* dinv  = (float*)(ws + off); off += degBytes;
  float* A     = (float*)(ws + off); off += hBytes;    // N x 64 (hlin)
  float* B     = (float*)(ws + off); off += hBytes;    // N x 64 (h out)
  int*   cnt   = (int*)(ws + off);   off += cntBytes;  // counts -> cursors
  int*   rp    = (int*)(ws + off);   off += rpBytes;   // N+1
  int*   srcs  = (int*)(ws + off);   off += srcBytes;  // E
  float* coefs = (float*)(ws + off); off += srcBytes;  // E (ws >= 83MB proven r4)
  int*   bsum  = (int*)(ws + off);                     // 128

  const int BLK = 256;
  const int nb = (N + 1023) / 1024;  // scan blocks; <=128 supported (N<=131072)

  // ---- CSR build + normalization ----
  hipMemsetAsync(cnt, 0, (size_t)N * 4, stream);
  k_count_int<<<(E + BLK - 1) / BLK, BLK, 0, stream>>>(dst, cnt, E);
  k_dinv<<<(N + BLK - 1) / BLK, BLK, 0, stream>>>(cnt, dinv, N);
  k_scan_block<<<nb, BLK, 0, stream>>>(cnt, rp, bsum, N);
  k_scan_bsum<<<1, 64, 0, stream>>>(bsum, nb);
  k_scan_add<<<(N + BLK - 1) / BLK, BLK, 0, stream>>>(rp, bsum, N, E);
  hipMemcpyAsync(cnt, rp, (size_t)N * 4, hipMemcpyDeviceToDevice, stream);  // cursors
  k_fill<<<(E + BLK - 1) / BLK, BLK, 0, stream>>>(src, dst, cnt, dinv, srcs, coefs, E);

  const int NPW = 16;  // nodes per wave in k_matmul_w
  const int mmGrid = (N + 4 * NPW - 1) / (4 * NPW);

  // ---- layer 1 ----
  k_matmul_w<128><<<mmGrid, BLK, 0, stream>>>(x, W1, A, N, NPW);
  k_gather<<<(N + 3) / 4, BLK, 0, stream>>>(A, rp, srcs, coefs, dinv, b1, B, N);

  // ---- layer 2 ----
  k_matmul_w<64><<<mmGrid, BLK, 0, stream>>>(B, W2, A, N, NPW);
  k_gather<<<(N + 3) / 4, BLK, 0, stream>>>(A, rp, srcs, coefs, dinv, b2, B, N);

  // ---- edge head: 256 pairs per 512-thread block ----
  k_edge_head<<<(P + 255) / 256, 512, 0, stream>>>(B, ep, M1, mb1, M2, mb2, out, P);
}